// Round 9
// baseline (183.158 us; speedup 1.0000x reference)
//
#include <hip/hip_runtime.h>

typedef __attribute__((ext_vector_type(4))) float f32x4;
typedef __attribute__((ext_vector_type(8))) short short8;
typedef __attribute__((ext_vector_type(4))) unsigned short us4;
typedef __attribute__((ext_vector_type(4))) unsigned int u32x4;

#define PMOD 113
#define NPAIR 12769
#define DM 1024
#define DMLP 4096
#define NBATCH 16384
#define SQRT3_2 0.86602540378443865f
#define CSTEP 6.1359231515425649e-3f   // 2*pi/1024
#define NZ 8
#define HPELEMS (228 * 4224)

__device__ __forceinline__ short f2bf(float x) {
    unsigned int u = __builtin_bit_cast(unsigned int, x);
    u += 0x7FFFu + ((u >> 16) & 1u);
    return (short)(u >> 16);
}
__device__ __forceinline__ float bf2f(short s) {
    return __builtin_bit_cast(float, (unsigned int)(unsigned short)s << 16);
}
__device__ __forceinline__ void cvt16(const float* p, short8& o0, short8& o1) {
    #pragma unroll
    for (int c4 = 0; c4 < 4; ++c4) {
        f32x4 v = *(const f32x4*)(p + c4 * 4);
        #pragma unroll
        for (int e = 0; e < 4; ++e) {
            short s = f2bf(v[e]);
            if (c4 < 2) o0[c4 * 4 + e] = s; else o1[(c4 - 2) * 4 + e] = s;
        }
    }
}

// ---------------------------------------------------------------------------
// k_prep: merged elementwise precompute. blockIdx.x ranges:
//   [0,1024)      : Fb[f][k] folded DFT basis (bf16)
//   [1024,1252)   : V2b[t][k] folded coefficients (bf16), rows 226/227 zero
//   [1252,2276)   : Wob = transpose(Wo) as bf16, 64x64 tiles
//   [2276,3300)   : Wib = bf16(Wi), flat 4096 elems/block
//   [3300,3329)   : Ub  = bf16(U),  flat 4096 elems/block (guarded)
// ---------------------------------------------------------------------------
__global__ __launch_bounds__(256) void k_prep(
    unsigned short* __restrict__ Fb, unsigned short* __restrict__ V2b,
    unsigned short* __restrict__ Wob, unsigned short* __restrict__ Wib,
    unsigned short* __restrict__ Ub,
    const float* __restrict__ E, const float* __restrict__ pos,
    const float* __restrict__ Wo, const float* __restrict__ Wi,
    const float* __restrict__ U)
{
    __shared__ float smem[64 * 65];
    const int blk = blockIdx.x, tid = threadIdx.x;

    if (blk < 1024) {
        const int f = blk;
        for (int k = tid; k < DM; k += 256) {
            float v;
            if (k <= 512) v = cosf((float)((f * k) & 1023) * CSTEP);
            else          v = sinf((float)((f * (k - 512)) & 1023) * CSTEP);
            Fb[f * DM + k] = (unsigned short)f2bf(v);
        }
    } else if (blk < 1252) {
        const int t = blk - 1024;
        if (t >= 226) {
            for (int k = tid; k < DM; k += 256) V2b[t * DM + k] = 0;
            return;
        }
        float* vc = smem;
        float* vs = smem + 1024;
        if (t < PMOD) {
            const float* e = E + t * DM;
            const float* e2 = E + PMOD * DM;
            for (int d = tid; d < DM; d += 256) {
                float e2v = e2[d] + pos[2 * DM + d];
                vc[d] = e[d] + pos[d] - 0.5f * pos[DM + d] - 0.5f * e2v;
                vs[d] = SQRT3_2 * (pos[DM + d] - e2v);
            }
        } else {
            const float* e = E + (t - PMOD) * DM;
            for (int d = tid; d < DM; d += 256) {
                float x = e[d];
                vc[d] = -0.5f * x;
                vs[d] = SQRT3_2 * x;
            }
        }
        __syncthreads();
        for (int k = tid; k < DM; k += 256) {
            float o;
            if (k == 0)        o = vc[0];
            else if (k < 512)  o = vc[k] + vc[1024 - k];
            else if (k == 512) o = vc[512];
            else               o = vs[k - 512] - vs[1536 - k];
            V2b[t * DM + k] = (unsigned short)f2bf(o);
        }
    } else if (blk < 2276) {
        const int idx = blk - 1252;
        const int m0 = (idx & 63) * 64;
        const int d0 = (idx >> 6) * 64;
        float (*tile)[65] = (float(*)[65])smem;
        #pragma unroll
        for (int it = 0; it < 16; ++it) {
            int i2 = tid + it * 256;
            int r = i2 >> 6, c = i2 & 63;
            tile[c][r] = Wo[(d0 + r) * DMLP + m0 + c];
        }
        __syncthreads();
        #pragma unroll
        for (int it = 0; it < 16; ++it) {
            int i2 = tid + it * 256;
            int r = i2 >> 6, c = i2 & 63;
            Wob[(m0 + r) * DM + d0 + c] = (unsigned short)f2bf(tile[r][c]);
        }
    } else if (blk < 3300) {
        const int eb = (blk - 2276) * 4096 + tid * 16;
        short8 o0, o1;
        cvt16(Wi + eb, o0, o1);
        *(short8*)&Wib[eb] = o0;
        *(short8*)&Wib[eb + 8] = o1;
    } else {
        const int eb = (blk - 3300) * 4096 + tid * 16;
        if (eb < PMOD * DM) {
            short8 o0, o1;
            cvt16(U + eb, o0, o1);
            *(short8*)&Ub[eb] = o0;
            *(short8*)&Ub[eb + 8] = o1;
        }
    }
}

// ---------------------------------------------------------------------------
// bf16 MFMA NT GEMM body, BM=BN=64, BK=64, 4 waves (2x2), per-wave 32x32.
// MODE 0: Tb = V2b . Fb^T ; rows<113 += e2; row227 += bo (bf16 out)
// MODE 1: A=Tb, B=[Wib;Ub] (N=4224); writes f32 partials C2f[r*4224+cg]
// MODE 2: Mb = Ub . Wob^T (bf16 out)
// ---------------------------------------------------------------------------
template<int MODE>
__device__ __forceinline__ void mfma_body(
    int n0, int row0, int kbeg, int kend, int Arows,
    unsigned short* __restrict__ C1, float* __restrict__ C2f,
    const unsigned short* __restrict__ A, const unsigned short* __restrict__ B1,
    const unsigned short* __restrict__ B2,
    const float* __restrict__ E, const float* __restrict__ pos,
    const float* __restrict__ bo, short* sA, short* sB)
{
    const int tid = threadIdx.x;
    const int sr = tid >> 2, sq = (tid & 3) * 16;
    const int lane = tid & 63, w = tid >> 6;
    const int wr = w >> 1, wc = w & 1;
    const int lr = lane & 15, lg = lane >> 4;

    const unsigned short* Ab = (row0 + sr < Arows) ? (A + (row0 + sr) * DM) : nullptr;
    const unsigned short* Bb;
    {
        int n = n0 + sr;
        if (MODE == 1) {
            if (n < 4096) Bb = B1 + n * DM;
            else if (n - 4096 < PMOD) Bb = B2 + (n - 4096) * DM;
            else Bb = nullptr;
        } else {
            Bb = B1 + n * DM;
        }
    }

    f32x4 acc[2][2];
    #pragma unroll
    for (int i = 0; i < 2; ++i)
        #pragma unroll
        for (int j = 0; j < 2; ++j) acc[i][j] = 0.f;

    for (int k0 = kbeg; k0 < kend; k0 += 64) {
        short8 a0, a1, b0, b1;
        if (Ab) { a0 = ((const short8*)(Ab + k0 + sq))[0];
                  a1 = ((const short8*)(Ab + k0 + sq))[1]; }
        else { a0 = 0; a1 = 0; }
        if (Bb) { b0 = ((const short8*)(Bb + k0 + sq))[0];
                  b1 = ((const short8*)(Bb + k0 + sq))[1]; }
        else { b0 = 0; b1 = 0; }
        if (k0 != kbeg) __syncthreads();
        *(short8*)&sA[sr * 72 + sq] = a0;
        *(short8*)&sA[sr * 72 + sq + 8] = a1;
        *(short8*)&sB[sr * 72 + sq] = b0;
        *(short8*)&sB[sr * 72 + sq + 8] = b1;
        __syncthreads();

        #pragma unroll
        for (int ks = 0; ks < 2; ++ks) {
            short8 af[2], bfr[2];
            #pragma unroll
            for (int i = 0; i < 2; ++i)
                af[i] = *(const short8*)&sA[(wr * 32 + i * 16 + lr) * 72 + ks * 32 + lg * 8];
            #pragma unroll
            for (int j = 0; j < 2; ++j)
                bfr[j] = *(const short8*)&sB[(wc * 32 + j * 16 + lr) * 72 + ks * 32 + lg * 8];
            #pragma unroll
            for (int i = 0; i < 2; ++i)
                #pragma unroll
                for (int j = 0; j < 2; ++j)
                    acc[i][j] = __builtin_amdgcn_mfma_f32_16x16x32_bf16(af[i], bfr[j], acc[i][j], 0, 0, 0);
        }
    }

    #pragma unroll
    for (int i = 0; i < 2; ++i) {
        #pragma unroll
        for (int q = 0; q < 4; ++q) {
            int r = row0 + wr * 32 + i * 16 + lg * 4 + q;
            #pragma unroll
            for (int j = 0; j < 2; ++j) {
                int cg = n0 + wc * 32 + j * 16 + lr;
                float v = acc[i][j][q];
                if (MODE == 0) {
                    if (r < 228) {
                        if (r < PMOD) v += E[PMOD * DM + cg] + pos[2 * DM + cg];
                        if (r == 227) v += bo[cg];
                        C1[r * DM + cg] = (unsigned short)f2bf(v);
                    }
                } else if (MODE == 1) {
                    if (r < 228) C2f[r * 4224 + cg] = v;
                } else {
                    if (r < 128) C1[r * DMLP + cg] = (unsigned short)f2bf(v);
                }
            }
        }
    }
}

// Merged MODE0 (64 blocks) + MODE2 (128 blocks): independent, fill the chip.
__global__ __launch_bounds__(256) void k_m02(
    unsigned short* __restrict__ Tb, unsigned short* __restrict__ Mb,
    const unsigned short* __restrict__ V2b, const unsigned short* __restrict__ Fb,
    const unsigned short* __restrict__ Ub, const unsigned short* __restrict__ Wob,
    const float* __restrict__ E, const float* __restrict__ pos,
    const float* __restrict__ bo)
{
    __shared__ short sA[64 * 72];
    __shared__ short sB[64 * 72];
    const int blk = blockIdx.x;
    if (blk < 64) {
        mfma_body<0>((blk & 15) * 64, (blk >> 4) * 64, 0, DM, 228, Tb, nullptr,
                     V2b, Fb, nullptr, E, pos, bo, sA, sB);
    } else {
        int i = blk - 64;
        mfma_body<2>((i & 63) * 64, (i >> 6) * 64, 0, DM, PMOD, Mb, nullptr,
                     Ub, Wob, nullptr, nullptr, nullptr, nullptr, sA, sB);
    }
}

// MODE1 split-K=4: grid (66, 4, 4); z-slice writes f32 partials Hp[z].
__global__ __launch_bounds__(256) void k_m1(
    float* __restrict__ Hp,
    const unsigned short* __restrict__ Tb, const unsigned short* __restrict__ Wib,
    const unsigned short* __restrict__ Ub)
{
    __shared__ short sA[64 * 72];
    __shared__ short sB[64 * 72];
    const int kbeg = blockIdx.z * 256;
    mfma_body<1>(blockIdx.x * 64, blockIdx.y * 64, kbeg, kbeg + 256, 228,
                 nullptr, Hp + (size_t)blockIdx.z * HPELEMS,
                 Tb, Wib, Ub, nullptr, nullptr, nullptr, sA, sB);
}

// ---------------------------------------------------------------------------
// hred: Hb[row][m] = bf16(sum_z Hp + (row<113 ? bi[m] : 0));  cols>=4096 -> L
// ---------------------------------------------------------------------------
__global__ __launch_bounds__(256) void k_hred(
    unsigned short* __restrict__ Hb, float* __restrict__ L,
    const float* __restrict__ Hp, const float* __restrict__ bi)
{
    const int e = (blockIdx.x * 256 + threadIdx.x) * 4;
    if (e >= HPELEMS) return;
    f32x4 s = *(const f32x4*)(Hp + e);
    #pragma unroll
    for (int z = 1; z < 4; ++z) s += *(const f32x4*)(Hp + (size_t)z * HPELEMS + e);
    unsigned int row = (unsigned)e / 4224u;
    unsigned int col = (unsigned)e - row * 4224u;
    if (col < 4096) {
        if (row < PMOD) s += *(const f32x4*)(bi + col);
        us4 o;
        #pragma unroll
        for (int j = 0; j < 4; ++j) o[j] = (unsigned short)f2bf(s[j]);
        *(us4*)&Hb[row * DMLP + col] = o;
    } else {
        *(f32x4*)&L[row * 128 + (col - 4096)] = s;
    }
}

// ---------------------------------------------------------------------------
// Pair GEMM: M=12769 pairs, N=128, K=4096. BM=128, BN=128, BK=64.
// 4 waves (2x2), wave tile 64x64. Grid (100 M-tiles, NZ=8 K-slices).
// LDS only for the h tile (double-buffered, ONE barrier per K-step).
// M (B-operand) fragments loaded DIRECTLY from L2-resident Mb into VGPRs.
// h rows on the fly: relu(Hb[a]+Hb[113+b]), truncating bf16 pack.
// Partials stored bf16 at LTp[p][z][128].
// ---------------------------------------------------------------------------
__global__ __launch_bounds__(256) void k_pair_gemm(
    unsigned short* __restrict__ LTp,
    const unsigned short* __restrict__ Hb,
    const unsigned short* __restrict__ Mb,
    const float* __restrict__ L)
{
    __shared__ short sH[2][128 * 72];   // 2 x 18 KB

    const int tid = threadIdx.x;
    const int p0 = blockIdx.x * 128;
    const int z = blockIdx.y;
    const int kbeg = z * 512;
    const bool slice0 = (z == 0);

    // h staging: 2 threads per row (hr), 32 k each (kh)
    const int hr = tid >> 1, kh = (tid & 1) * 32;
    const unsigned int pc = (unsigned)min(p0 + hr, NPAIR - 1);
    const unsigned int a_r = pc / 113u;
    const unsigned int b_r = pc - a_r * 113u;
    const unsigned short* pHA = Hb + a_r * DMLP + kbeg + kh;
    const unsigned short* pHB = Hb + (PMOD + b_r) * DMLP + kbeg + kh;

    const int lane = tid & 63, w = tid >> 6;
    const int wr = w >> 1, wc = w & 1;
    const int lr = lane & 15, lg = lane >> 4;

    // direct-B row pointers (per-thread MFMA B fragments)
    const unsigned short* pM[4];
    #pragma unroll
    for (int j = 0; j < 4; ++j)
        pM[j] = Mb + (wc * 64 + j * 16 + lr) * DMLP + kbeg + lg * 8;

    f32x4 acc[4][4];
    #pragma unroll
    for (int i = 0; i < 4; ++i)
        #pragma unroll
        for (int j = 0; j < 4; ++j) acc[i][j] = 0.f;

    short8 rA[4], rB[4];
    #pragma unroll
    for (int c = 0; c < 4; ++c) {
        rA[c] = *(const short8*)(pHA + c * 8);
        rB[c] = *(const short8*)(pHB + c * 8);
    }

    #pragma unroll 1
    for (int t = 0; t < 8; ++t) {
        // issue this step's B fragments early
        short8 rM0[4], rM1[4];
        #pragma unroll
        for (int j = 0; j < 4; ++j) {
            rM0[j] = *(const short8*)(pM[j] + t * 64);
            rM1[j] = *(const short8*)(pM[j] + t * 64 + 32);
        }

        // h = relu(HA + HB), truncating bf16 pack
        short8 u[4];
        #pragma unroll
        for (int c = 0; c < 4; ++c) {
            u32x4 up;
            #pragma unroll
            for (int e = 0; e < 4; ++e) {
                float f0 = fmaxf(bf2f(rA[c][2 * e])     + bf2f(rB[c][2 * e]),     0.f);
                float f1 = fmaxf(bf2f(rA[c][2 * e + 1]) + bf2f(rB[c][2 * e + 1]), 0.f);
                up[e] = (__builtin_bit_cast(unsigned int, f1) & 0xffff0000u)
                      | (__builtin_bit_cast(unsigned int, f0) >> 16);
            }
            u[c] = __builtin_bit_cast(short8, up);
        }

        // prefetch next step's h inputs
        if (t < 7) {
            #pragma unroll
            for (int c = 0; c < 4; ++c) {
                rA[c] = *(const short8*)(pHA + (t + 1) * 64 + c * 8);
                rB[c] = *(const short8*)(pHB + (t + 1) * 64 + c * 8);
            }
        }

        // stage h (double buffer) — one barrier per step
        #pragma unroll
        for (int c = 0; c < 4; ++c)
            *(short8*)&sH[t & 1][hr * 72 + kh + c * 8] = u[c];
        __syncthreads();

        #pragma unroll
        for (int ks = 0; ks < 2; ++ks) {
            short8 af[4];
            #pragma unroll
            for (int i = 0; i < 4; ++i)
                af[i] = *(const short8*)&sH[t & 1][(wr * 64 + i * 16 + lr) * 72 + ks * 32 + lg * 8];
            #pragma unroll
            for (int i = 0; i < 4; ++i)
                #pragma unroll
                for (int j = 0; j < 4; ++j)
                    acc[i][j] = __builtin_amdgcn_mfma_f32_16x16x32_bf16(
                        af[i], ks ? rM1[j] : rM0[j], acc[i][j], 0, 0, 0);
        }
    }

    const float* Lb0 = L + PMOD * 128;
    const float* Lc = L + 227 * 128;
    #pragma unroll
    for (int i = 0; i < 4; ++i) {
        #pragma unroll
        for (int q = 0; q < 4; ++q) {
            int p = p0 + wr * 64 + i * 16 + lg * 4 + q;
            if (p >= NPAIR) continue;
            unsigned int pa = (unsigned)p / 113u;
            unsigned int pb = (unsigned)p - pa * 113u;
            unsigned short* dst = LTp + ((size_t)p * NZ + z) * 128;
            const float* La = L + pa * 128;
            const float* Lb = Lb0 + pb * 128;
            #pragma unroll
            for (int j = 0; j < 4; ++j) {
                int col = wc * 64 + j * 16 + lr;
                float val = acc[i][j][q];
                if (slice0) val += La[col] + Lb[col] + Lc[col];
                dst[col] = (unsigned short)f2bf(val);
            }
        }
    }
}

// ---------------------------------------------------------------------------
// Gather: out[i][v] = sum_z LTp[pair_i][z][v].  16 threads per batch element;
// each element's 8 partial rows are one contiguous 2KB chunk.
// ---------------------------------------------------------------------------
__global__ __launch_bounds__(256) void k_gather(
    float* __restrict__ out, const unsigned short* __restrict__ LTp,
    const int* __restrict__ a, const int* __restrict__ b)
{
    const int tid = threadIdx.x;
    const int elem = blockIdx.x * 16 + (tid >> 4);
    const int t16 = tid & 15;
    const int v0 = t16 * 8;
    if (v0 > 112) return;
    unsigned int pair = (unsigned)a[elem] * 113u + (unsigned)b[elem];
    const unsigned short* src = LTp + (size_t)pair * (NZ * 128) + v0;
    float s[8];
    #pragma unroll
    for (int e = 0; e < 8; ++e) s[e] = 0.f;
    #pragma unroll
    for (int z = 0; z < NZ; ++z) {
        short8 vv = *(const short8*)(src + z * 128);
        #pragma unroll
        for (int e = 0; e < 8; ++e) s[e] += bf2f(vv[e]);
    }
    float* o = out + (size_t)elem * PMOD + v0;
    const int nv = (v0 + 8 <= PMOD) ? 8 : (PMOD - v0);
    for (int e = 0; e < nv; ++e) o[e] = s[e];
}

// ---------------------------------------------------------------------------
extern "C" void kernel_launch(void* const* d_in, const int* in_sizes, int n_in,
                              void* d_out, int out_size, void* d_ws, size_t ws_size,
                              hipStream_t stream)
{
    const int*   a   = (const int*)d_in[0];
    const int*   b   = (const int*)d_in[1];
    const float* E   = (const float*)d_in[2];
    const float* pos = (const float*)d_in[3];
    const float* Wi  = (const float*)d_in[4];
    const float* bi  = (const float*)d_in[5];
    const float* Wo  = (const float*)d_in[6];
    const float* bo  = (const float*)d_in[7];
    const float* U   = (const float*)d_in[8];
    float* out = (float*)d_out;

    unsigned short* Fb  = (unsigned short*)d_ws;          // 1024*1024
    unsigned short* V2b = Fb + 1024 * 1024;               // 228*1024
    unsigned short* Tb  = V2b + 228 * 1024;               // 228*1024
    unsigned short* Hb  = Tb + 228 * 1024;                // 228*4096
    unsigned short* Wob = Hb + 228 * 4096;                // 4096*1024
    unsigned short* Mb  = Wob + 4096 * 1024;              // 128*4096
    unsigned short* Wib = Mb + 128 * 4096;                // 4096*1024
    unsigned short* Ub  = Wib + 4096 * 1024;              // 113*1024 (pad 116)
    unsigned short* LTp = Ub + 116 * 1024;                // 12800*NZ*128
    float* L  = (float*)(LTp + (size_t)12800 * NZ * 128); // 228*128
    float* Hp = L + 228 * 128;                            // 4 * 228*4224

    k_prep<<<3329, 256, 0, stream>>>(Fb, V2b, Wob, Wib, Ub, E, pos, Wo, Wi, U);
    k_m02<<<192, 256, 0, stream>>>(Tb, Mb, V2b, Fb, Ub, Wob, E, pos, bo);
    k_m1<<<dim3(66, 4, 4), 256, 0, stream>>>(Hp, Tb, Wib, Ub);
    k_hred<<<(HPELEMS / 4 + 255) / 256, 256, 0, stream>>>(Hb, L, Hp, bi);
    k_pair_gemm<<<dim3(100, NZ), 256, 0, stream>>>(LTp, Hb, Mb, L);
    k_gather<<<NBATCH / 16, 256, 0, stream>>>(out, LTp, a, b);

    (void)in_sizes; (void)n_in; (void)out_size; (void)ws_size;
}

// Round 10
// 166.773 us; speedup vs baseline: 1.0982x; 1.0982x over previous
//
#include <hip/hip_runtime.h>

typedef __attribute__((ext_vector_type(4))) float f32x4;
typedef __attribute__((ext_vector_type(8))) short short8;
typedef __attribute__((ext_vector_type(4))) unsigned short us4;
typedef __attribute__((ext_vector_type(4))) unsigned int u32x4;

#define PMOD 113
#define NPAIR 12769
#define DM 1024
#define DMLP 4096
#define NBATCH 16384
#define SQRT3_2 0.86602540378443865f
#define CSTEP 6.1359231515425649e-3f   // 2*pi/1024
#define NZ 8
#define HPELEMS (228 * 4224)
#define HREDB ((HPELEMS / 4 + 255) / 256)   // 941

__device__ __forceinline__ short f2bf(float x) {
    unsigned int u = __builtin_bit_cast(unsigned int, x);
    u += 0x7FFFu + ((u >> 16) & 1u);
    return (short)(u >> 16);
}
__device__ __forceinline__ float bf2f(short s) {
    return __builtin_bit_cast(float, (unsigned int)(unsigned short)s << 16);
}
__device__ __forceinline__ void cvt16(const float* p, short8& o0, short8& o1) {
    #pragma unroll
    for (int c4 = 0; c4 < 4; ++c4) {
        f32x4 v = *(const f32x4*)(p + c4 * 4);
        #pragma unroll
        for (int e = 0; e < 4; ++e) {
            short s = f2bf(v[e]);
            if (c4 < 2) o0[c4 * 4 + e] = s; else o1[(c4 - 2) * 4 + e] = s;
        }
    }
}

// ---------------------------------------------------------------------------
// k_prep: merged elementwise precompute. blockIdx.x ranges:
//   [0,1024)      : Fb[f][k] folded DFT basis (bf16)
//   [1024,1252)   : V2b[t][k] folded coefficients (bf16), rows 226/227 zero
//   [1252,2276)   : Wob = transpose(Wo) as bf16, 64x64 tiles
//   [2276,3300)   : Wib = bf16(Wi), flat 4096 elems/block
//   [3300,3329)   : Ub  = bf16(U),  flat 4096 elems/block (guarded)
// ---------------------------------------------------------------------------
__global__ __launch_bounds__(256) void k_prep(
    unsigned short* __restrict__ Fb, unsigned short* __restrict__ V2b,
    unsigned short* __restrict__ Wob, unsigned short* __restrict__ Wib,
    unsigned short* __restrict__ Ub,
    const float* __restrict__ E, const float* __restrict__ pos,
    const float* __restrict__ Wo, const float* __restrict__ Wi,
    const float* __restrict__ U)
{
    __shared__ float smem[64 * 65];
    const int blk = blockIdx.x, tid = threadIdx.x;

    if (blk < 1024) {
        const int f = blk;
        for (int k = tid; k < DM; k += 256) {
            float v;
            if (k <= 512) v = cosf((float)((f * k) & 1023) * CSTEP);
            else          v = sinf((float)((f * (k - 512)) & 1023) * CSTEP);
            Fb[f * DM + k] = (unsigned short)f2bf(v);
        }
    } else if (blk < 1252) {
        const int t = blk - 1024;
        if (t >= 226) {
            for (int k = tid; k < DM; k += 256) V2b[t * DM + k] = 0;
            return;
        }
        float* vc = smem;
        float* vs = smem + 1024;
        if (t < PMOD) {
            const float* e = E + t * DM;
            const float* e2 = E + PMOD * DM;
            for (int d = tid; d < DM; d += 256) {
                float e2v = e2[d] + pos[2 * DM + d];
                vc[d] = e[d] + pos[d] - 0.5f * pos[DM + d] - 0.5f * e2v;
                vs[d] = SQRT3_2 * (pos[DM + d] - e2v);
            }
        } else {
            const float* e = E + (t - PMOD) * DM;
            for (int d = tid; d < DM; d += 256) {
                float x = e[d];
                vc[d] = -0.5f * x;
                vs[d] = SQRT3_2 * x;
            }
        }
        __syncthreads();
        for (int k = tid; k < DM; k += 256) {
            float o;
            if (k == 0)        o = vc[0];
            else if (k < 512)  o = vc[k] + vc[1024 - k];
            else if (k == 512) o = vc[512];
            else               o = vs[k - 512] - vs[1536 - k];
            V2b[t * DM + k] = (unsigned short)f2bf(o);
        }
    } else if (blk < 2276) {
        const int idx = blk - 1252;
        const int m0 = (idx & 63) * 64;
        const int d0 = (idx >> 6) * 64;
        float (*tile)[65] = (float(*)[65])smem;
        #pragma unroll
        for (int it = 0; it < 16; ++it) {
            int i2 = tid + it * 256;
            int r = i2 >> 6, c = i2 & 63;
            tile[c][r] = Wo[(d0 + r) * DMLP + m0 + c];
        }
        __syncthreads();
        #pragma unroll
        for (int it = 0; it < 16; ++it) {
            int i2 = tid + it * 256;
            int r = i2 >> 6, c = i2 & 63;
            Wob[(m0 + r) * DM + d0 + c] = (unsigned short)f2bf(tile[r][c]);
        }
    } else if (blk < 3300) {
        const int eb = (blk - 2276) * 4096 + tid * 16;
        short8 o0, o1;
        cvt16(Wi + eb, o0, o1);
        *(short8*)&Wib[eb] = o0;
        *(short8*)&Wib[eb + 8] = o1;
    } else {
        const int eb = (blk - 3300) * 4096 + tid * 16;
        if (eb < PMOD * DM) {
            short8 o0, o1;
            cvt16(U + eb, o0, o1);
            *(short8*)&Ub[eb] = o0;
            *(short8*)&Ub[eb + 8] = o1;
        }
    }
}

// ---------------------------------------------------------------------------
// bf16 MFMA NT GEMM body, BM=BN=64, BK=64, 4 waves (2x2), per-wave 32x32.
// MODE 0: Tb = V2b . Fb^T ; rows<113 += e2; row227 += bo (bf16 out)
// MODE 1: A=Tb, B=[Wib;Ub] (N=4224); writes f32 partials C2f[r*4224+cg]
// MODE 2: Mb = Ub . Wob^T (bf16 out)
// ---------------------------------------------------------------------------
template<int MODE>
__device__ __forceinline__ void mfma_body(
    int n0, int row0, int kbeg, int kend, int Arows,
    unsigned short* __restrict__ C1, float* __restrict__ C2f,
    const unsigned short* __restrict__ A, const unsigned short* __restrict__ B1,
    const unsigned short* __restrict__ B2,
    const float* __restrict__ E, const float* __restrict__ pos,
    const float* __restrict__ bo, short* sA, short* sB)
{
    const int tid = threadIdx.x;
    const int sr = tid >> 2, sq = (tid & 3) * 16;
    const int lane = tid & 63, w = tid >> 6;
    const int wr = w >> 1, wc = w & 1;
    const int lr = lane & 15, lg = lane >> 4;

    const unsigned short* Ab = (row0 + sr < Arows) ? (A + (row0 + sr) * DM) : nullptr;
    const unsigned short* Bb;
    {
        int n = n0 + sr;
        if (MODE == 1) {
            if (n < 4096) Bb = B1 + n * DM;
            else if (n - 4096 < PMOD) Bb = B2 + (n - 4096) * DM;
            else Bb = nullptr;
        } else {
            Bb = B1 + n * DM;
        }
    }

    f32x4 acc[2][2];
    #pragma unroll
    for (int i = 0; i < 2; ++i)
        #pragma unroll
        for (int j = 0; j < 2; ++j) acc[i][j] = 0.f;

    for (int k0 = kbeg; k0 < kend; k0 += 64) {
        short8 a0, a1, b0, b1;
        if (Ab) { a0 = ((const short8*)(Ab + k0 + sq))[0];
                  a1 = ((const short8*)(Ab + k0 + sq))[1]; }
        else { a0 = 0; a1 = 0; }
        if (Bb) { b0 = ((const short8*)(Bb + k0 + sq))[0];
                  b1 = ((const short8*)(Bb + k0 + sq))[1]; }
        else { b0 = 0; b1 = 0; }
        if (k0 != kbeg) __syncthreads();
        *(short8*)&sA[sr * 72 + sq] = a0;
        *(short8*)&sA[sr * 72 + sq + 8] = a1;
        *(short8*)&sB[sr * 72 + sq] = b0;
        *(short8*)&sB[sr * 72 + sq + 8] = b1;
        __syncthreads();

        #pragma unroll
        for (int ks = 0; ks < 2; ++ks) {
            short8 af[2], bfr[2];
            #pragma unroll
            for (int i = 0; i < 2; ++i)
                af[i] = *(const short8*)&sA[(wr * 32 + i * 16 + lr) * 72 + ks * 32 + lg * 8];
            #pragma unroll
            for (int j = 0; j < 2; ++j)
                bfr[j] = *(const short8*)&sB[(wc * 32 + j * 16 + lr) * 72 + ks * 32 + lg * 8];
            #pragma unroll
            for (int i = 0; i < 2; ++i)
                #pragma unroll
                for (int j = 0; j < 2; ++j)
                    acc[i][j] = __builtin_amdgcn_mfma_f32_16x16x32_bf16(af[i], bfr[j], acc[i][j], 0, 0, 0);
        }
    }

    #pragma unroll
    for (int i = 0; i < 2; ++i) {
        #pragma unroll
        for (int q = 0; q < 4; ++q) {
            int r = row0 + wr * 32 + i * 16 + lg * 4 + q;
            #pragma unroll
            for (int j = 0; j < 2; ++j) {
                int cg = n0 + wc * 32 + j * 16 + lr;
                float v = acc[i][j][q];
                if (MODE == 0) {
                    if (r < 228) {
                        if (r < PMOD) v += E[PMOD * DM + cg] + pos[2 * DM + cg];
                        if (r == 227) v += bo[cg];
                        C1[r * DM + cg] = (unsigned short)f2bf(v);
                    }
                } else if (MODE == 1) {
                    if (r < 228) C2f[r * 4224 + cg] = v;
                } else {
                    if (r < 128) C1[r * DMLP + cg] = (unsigned short)f2bf(v);
                }
            }
        }
    }
}

// Merged MODE0 (64 blocks) + MODE2 (128 blocks): independent, fill the chip.
__global__ __launch_bounds__(256) void k_m02(
    unsigned short* __restrict__ Tb, unsigned short* __restrict__ Mb,
    const unsigned short* __restrict__ V2b, const unsigned short* __restrict__ Fb,
    const unsigned short* __restrict__ Ub, const unsigned short* __restrict__ Wob,
    const float* __restrict__ E, const float* __restrict__ pos,
    const float* __restrict__ bo)
{
    __shared__ short sA[64 * 72];
    __shared__ short sB[64 * 72];
    const int blk = blockIdx.x;
    if (blk < 64) {
        mfma_body<0>((blk & 15) * 64, (blk >> 4) * 64, 0, DM, 228, Tb, nullptr,
                     V2b, Fb, nullptr, E, pos, bo, sA, sB);
    } else {
        int i = blk - 64;
        mfma_body<2>((i & 63) * 64, (i >> 6) * 64, 0, DM, PMOD, Mb, nullptr,
                     Ub, Wob, nullptr, nullptr, nullptr, nullptr, sA, sB);
    }
}

// MODE1 split-K=4: grid (66, 4, 4); z-slice writes f32 partials Hp[z].
__global__ __launch_bounds__(256) void k_m1(
    float* __restrict__ Hp,
    const unsigned short* __restrict__ Tb, const unsigned short* __restrict__ Wib,
    const unsigned short* __restrict__ Ub)
{
    __shared__ short sA[64 * 72];
    __shared__ short sB[64 * 72];
    const int kbeg = blockIdx.z * 256;
    mfma_body<1>(blockIdx.x * 64, blockIdx.y * 64, kbeg, kbeg + 256, 228,
                 nullptr, Hp + (size_t)blockIdx.z * HPELEMS,
                 Tb, Wib, Ub, nullptr, nullptr, nullptr, sA, sB);
}

// ---------------------------------------------------------------------------
// hred: blocks [0,941): Hb[row][m] = bf16(sum_z Hp + bias); cols>=4096 -> L.
// blocks [941,1197): Mt fragment-transpose of Mb:
//   Mt[(k8*128 + v)*8 + e] = Mb[v][k8*8 + e]
// ---------------------------------------------------------------------------
__global__ __launch_bounds__(256) void k_hred(
    unsigned short* __restrict__ Hb, float* __restrict__ L,
    const float* __restrict__ Hp, const float* __restrict__ bi,
    unsigned short* __restrict__ Mt, const unsigned short* __restrict__ Mb)
{
    const int tid = threadIdx.x;
    if (blockIdx.x >= HREDB) {
        // Mt transpose: idx8 = v*512 + k8 (lanes walk k8 -> coalesced reads)
        const int idx8 = (blockIdx.x - HREDB) * 256 + tid;
        const int v = idx8 >> 9;
        const int k8 = idx8 & 511;
        short8 d = *(const short8*)(Mb + v * DMLP + k8 * 8);
        *(short8*)&Mt[((size_t)k8 * 128 + v) * 8] = d;
        return;
    }
    const int e = (blockIdx.x * 256 + tid) * 4;
    if (e >= HPELEMS) return;
    f32x4 s = *(const f32x4*)(Hp + e);
    #pragma unroll
    for (int z = 1; z < 4; ++z) s += *(const f32x4*)(Hp + (size_t)z * HPELEMS + e);
    unsigned int row = (unsigned)e / 4224u;
    unsigned int col = (unsigned)e - row * 4224u;
    if (col < 4096) {
        if (row < PMOD) s += *(const f32x4*)(bi + col);
        us4 o;
        #pragma unroll
        for (int j = 0; j < 4; ++j) o[j] = (unsigned short)f2bf(s[j]);
        *(us4*)&Hb[row * DMLP + col] = o;
    } else {
        *(f32x4*)&L[row * 128 + (col - 4096)] = s;
    }
}

// ---------------------------------------------------------------------------
// Pair GEMM: M=12769 pairs, N=128, K=4096. BM=128, BN=128, BK=64.
// 4 waves (2x2), wave tile 64x64. Grid (100 M-tiles, NZ=8 K-slices).
// LDS only for h (double buffer, ONE barrier per K-step).
// B fragments loaded directly from fragment-layout Mt (coalesced, L2-hot).
// ---------------------------------------------------------------------------
__global__ __launch_bounds__(256) void k_pair_gemm(
    unsigned short* __restrict__ LTp,
    const unsigned short* __restrict__ Hb,
    const unsigned short* __restrict__ Mt,
    const float* __restrict__ L)
{
    __shared__ short sH[2][128 * 72];   // 2 x 18 KB

    const int tid = threadIdx.x;
    const int p0 = blockIdx.x * 128;
    const int z = blockIdx.y;
    const int kbeg = z * 512;
    const bool slice0 = (z == 0);

    // h staging: 2 threads per row (hr), 32 k each (kh)
    const int hr = tid >> 1, kh = (tid & 1) * 32;
    const unsigned int pc = (unsigned)min(p0 + hr, NPAIR - 1);
    const unsigned int a_r = pc / 113u;
    const unsigned int b_r = pc - a_r * 113u;
    const unsigned short* pHA = Hb + a_r * DMLP + kbeg + kh;
    const unsigned short* pHB = Hb + (PMOD + b_r) * DMLP + kbeg + kh;

    const int lane = tid & 63, w = tid >> 6;
    const int wr = w >> 1, wc = w & 1;
    const int lr = lane & 15, lg = lane >> 4;

    // fragment-layout B base: ((kbeg/8 + lg)*128 + wc*64 + lr) * 8
    const unsigned short* pMt =
        Mt + ((size_t)((kbeg >> 3) + lg) * 128 + wc * 64 + lr) * 8;
    // offset(t, ks, j) = t*8192 + ks*4096 + j*128  (shorts)

    f32x4 acc[4][4];
    #pragma unroll
    for (int i = 0; i < 4; ++i)
        #pragma unroll
        for (int j = 0; j < 4; ++j) acc[i][j] = 0.f;

    short8 rA[4], rB[4];
    #pragma unroll
    for (int c = 0; c < 4; ++c) {
        rA[c] = *(const short8*)(pHA + c * 8);
        rB[c] = *(const short8*)(pHB + c * 8);
    }

    #pragma unroll 1
    for (int t = 0; t < 8; ++t) {
        // issue this step's B fragments early (coalesced, L2-resident)
        short8 rM0[4], rM1[4];
        #pragma unroll
        for (int j = 0; j < 4; ++j) {
            rM0[j] = *(const short8*)(pMt + t * 8192 + j * 128);
            rM1[j] = *(const short8*)(pMt + t * 8192 + 4096 + j * 128);
        }

        // h = relu(HA + HB), truncating bf16 pack
        short8 u[4];
        #pragma unroll
        for (int c = 0; c < 4; ++c) {
            u32x4 up;
            #pragma unroll
            for (int e = 0; e < 4; ++e) {
                float f0 = fmaxf(bf2f(rA[c][2 * e])     + bf2f(rB[c][2 * e]),     0.f);
                float f1 = fmaxf(bf2f(rA[c][2 * e + 1]) + bf2f(rB[c][2 * e + 1]), 0.f);
                up[e] = (__builtin_bit_cast(unsigned int, f1) & 0xffff0000u)
                      | (__builtin_bit_cast(unsigned int, f0) >> 16);
            }
            u[c] = __builtin_bit_cast(short8, up);
        }

        // prefetch next step's h inputs
        if (t < 7) {
            #pragma unroll
            for (int c = 0; c < 4; ++c) {
                rA[c] = *(const short8*)(pHA + (t + 1) * 64 + c * 8);
                rB[c] = *(const short8*)(pHB + (t + 1) * 64 + c * 8);
            }
        }

        // stage h (double buffer) — one barrier per step
        #pragma unroll
        for (int c = 0; c < 4; ++c)
            *(short8*)&sH[t & 1][hr * 72 + kh + c * 8] = u[c];
        __syncthreads();

        #pragma unroll
        for (int ks = 0; ks < 2; ++ks) {
            short8 af[4];
            #pragma unroll
            for (int i = 0; i < 4; ++i)
                af[i] = *(const short8*)&sH[t & 1][(wr * 64 + i * 16 + lr) * 72 + ks * 32 + lg * 8];
            #pragma unroll
            for (int i = 0; i < 4; ++i)
                #pragma unroll
                for (int j = 0; j < 4; ++j)
                    acc[i][j] = __builtin_amdgcn_mfma_f32_16x16x32_bf16(
                        af[i], ks ? rM1[j] : rM0[j], acc[i][j], 0, 0, 0);
        }
    }

    const float* Lb0 = L + PMOD * 128;
    const float* Lc = L + 227 * 128;
    #pragma unroll
    for (int i = 0; i < 4; ++i) {
        #pragma unroll
        for (int q = 0; q < 4; ++q) {
            int p = p0 + wr * 64 + i * 16 + lg * 4 + q;
            if (p >= NPAIR) continue;
            unsigned int pa = (unsigned)p / 113u;
            unsigned int pb = (unsigned)p - pa * 113u;
            unsigned short* dst = LTp + ((size_t)p * NZ + z) * 128;
            const float* La = L + pa * 128;
            const float* Lb = Lb0 + pb * 128;
            #pragma unroll
            for (int j = 0; j < 4; ++j) {
                int col = wc * 64 + j * 16 + lr;
                float val = acc[i][j][q];
                if (slice0) val += La[col] + Lb[col] + Lc[col];
                dst[col] = (unsigned short)f2bf(val);
            }
        }
    }
}

// ---------------------------------------------------------------------------
// Gather: out[i][v] = sum_z LTp[pair_i][z][v].  16 threads per batch element;
// each element's 8 partial rows are one contiguous 2KB chunk.
// ---------------------------------------------------------------------------
__global__ __launch_bounds__(256) void k_gather(
    float* __restrict__ out, const unsigned short* __restrict__ LTp,
    const int* __restrict__ a, const int* __restrict__ b)
{
    const int tid = threadIdx.x;
    const int elem = blockIdx.x * 16 + (tid >> 4);
    const int t16 = tid & 15;
    const int v0 = t16 * 8;
    if (v0 > 112) return;
    unsigned int pair = (unsigned)a[elem] * 113u + (unsigned)b[elem];
    const unsigned short* src = LTp + (size_t)pair * (NZ * 128) + v0;
    float s[8];
    #pragma unroll
    for (int e = 0; e < 8; ++e) s[e] = 0.f;
    #pragma unroll
    for (int z = 0; z < NZ; ++z) {
        short8 vv = *(const short8*)(src + z * 128);
        #pragma unroll
        for (int e = 0; e < 8; ++e) s[e] += bf2f(vv[e]);
    }
    float* o = out + (size_t)elem * PMOD + v0;
    const int nv = (v0 + 8 <= PMOD) ? 8 : (PMOD - v0);
    for (int e = 0; e < nv; ++e) o[e] = s[e];
}

// ---------------------------------------------------------------------------
extern "C" void kernel_launch(void* const* d_in, const int* in_sizes, int n_in,
                              void* d_out, int out_size, void* d_ws, size_t ws_size,
                              hipStream_t stream)
{
    const int*   a   = (const int*)d_in[0];
    const int*   b   = (const int*)d_in[1];
    const float* E   = (const float*)d_in[2];
    const float* pos = (const float*)d_in[3];
    const float* Wi  = (const float*)d_in[4];
    const float* bi  = (const float*)d_in[5];
    const float* Wo  = (const float*)d_in[6];
    const float* bo  = (const float*)d_in[7];
    const float* U   = (const float*)d_in[8];
    float* out = (float*)d_out;

    unsigned short* Fb  = (unsigned short*)d_ws;          // 1024*1024
    unsigned short* V2b = Fb + 1024 * 1024;               // 228*1024
    unsigned short* Tb  = V2b + 228 * 1024;               // 228*1024
    unsigned short* Hb  = Tb + 228 * 1024;                // 228*4096
    unsigned short* Wob = Hb + 228 * 4096;                // 4096*1024
    unsigned short* Mb  = Wob + 4096 * 1024;              // 128*4096
    unsigned short* Wib = Mb + 128 * 4096;                // 4096*1024
    unsigned short* Ub  = Wib + 4096 * 1024;              // 113*1024 (pad 116)
    unsigned short* Mt  = Ub + 116 * 1024;                // 512*128*8 = 1 MB
    unsigned short* LTp = Mt + 512 * 128 * 8;             // 12800*NZ*128
    float* L  = (float*)(LTp + (size_t)12800 * NZ * 128); // 228*128
    float* Hp = L + 228 * 128;                            // 4 * 228*4224

    k_prep<<<3329, 256, 0, stream>>>(Fb, V2b, Wob, Wib, Ub, E, pos, Wo, Wi, U);
    k_m02<<<192, 256, 0, stream>>>(Tb, Mb, V2b, Fb, Ub, Wob, E, pos, bo);
    k_m1<<<dim3(66, 4, 4), 256, 0, stream>>>(Hp, Tb, Wib, Ub);
    k_hred<<<HREDB + 256, 256, 0, stream>>>(Hb, L, Hp, bi, Mt, Mb);
    k_pair_gemm<<<dim3(100, NZ), 256, 0, stream>>>(LTp, Hb, Mt, L);
    k_gather<<<NBATCH / 16, 256, 0, stream>>>(out, LTp, a, b);

    (void)in_sizes; (void)n_in; (void)out_size; (void)ws_size;
}